// Round 8
// baseline (514.046 us; speedup 1.0000x reference)
//
#include <hip/hip_runtime.h>
#include <hip/hip_bf16.h>
#include <stdint.h>

typedef __hip_bfloat16 bf16;
using f32x4 = __attribute__((ext_vector_type(4))) float;
using s16x8 = __attribute__((ext_vector_type(8))) short;

#define MFMA16(A_, B_, C_) __builtin_amdgcn_mfma_f32_16x16x32_bf16((A_), (B_), (C_), 0, 0, 0)

__device__ __forceinline__ void gload16(const void* g, void* l) {
  __builtin_amdgcn_global_load_lds((const __attribute__((address_space(1))) void*)g,
                                   (__attribute__((address_space(3))) void*)l, 16, 0, 0);
}

// ---------------- dtype detector ----------------
// flag=1 -> inputs/outputs fp32; flag=0 -> bf16.
__global__ __launch_bounds__(256) void detect_kernel(const void* __restrict__ x,
                                                     int* __restrict__ flag) {
  __shared__ int cnt;
  if (threadIdx.x == 0) cnt = 0;
  __syncthreads();
  const uint32_t* w = (const uint32_t*)x;
  int local = 0;
#pragma unroll
  for (int i = 0; i < 8; ++i) {
    uint32_t v = w[threadIdx.x * 8 + i];
    uint32_t e = (v >> 7) & 0xFF;
    if (e >= 110 && e <= 135) local++;
  }
  atomicAdd(&cnt, local);
  __syncthreads();
  if (threadIdx.x == 0) *flag = (cnt < 1024) ? 1 : 0;
}

// ---------------- x chunk -> bf16 (vectorized) ----------------
__global__ __launch_bounds__(256) void convert_kernel(const void* __restrict__ x,
                                                      bf16* __restrict__ xb,
                                                      size_t elem_off,
                                                      const int* __restrict__ flag) {
  size_t i = ((size_t)blockIdx.x * 256 + threadIdx.x) * 8;
  if (*flag) {
    const float* xf = (const float*)x + elem_off + i;
    float4 a = ((const float4*)xf)[0];
    float4 b = ((const float4*)xf)[1];
    union { bf16 h[8]; uint4 u; } o;
    o.h[0] = __float2bfloat16(a.x); o.h[1] = __float2bfloat16(a.y);
    o.h[2] = __float2bfloat16(a.z); o.h[3] = __float2bfloat16(a.w);
    o.h[4] = __float2bfloat16(b.x); o.h[5] = __float2bfloat16(b.y);
    o.h[6] = __float2bfloat16(b.z); o.h[7] = __float2bfloat16(b.w);
    *(uint4*)(&xb[i]) = o.u;
  } else {
    *(uint4*)(&xb[i]) = *(const uint4*)((const bf16*)x + elem_off + i);
  }
}

// ---------------- transpose: Wt[n][k] = W[k][n], W is [K][N] ----------------
__global__ __launch_bounds__(256) void transpose_kernel(const void* __restrict__ W,
                                                        bf16* __restrict__ Wt,
                                                        int K, int N,
                                                        const int* __restrict__ flag) {
  int idx = blockIdx.x * 256 + threadIdx.x;
  if (idx >= K * N) return;
  int n = idx / K;
  int k = idx - n * K;
  if (*flag)
    Wt[idx] = __float2bfloat16(((const float*)W)[k * N + n]);
  else
    Wt[idx] = ((const bf16*)W)[k * N + n];
}

// ---------------- GEMM: C[M][N] = A[M][384] * Bt[N][384]^T ----------------
// Barrier-free N-loop structure (round-8): block owns a 64-row A panel,
// staged ONCE into LDS (48 KB, 12 gload16/thread, ONE barrier). Then for
// each 128-col N-tile (NT=9 for QKV / 3 for proj): A frags re-read from LDS
// (lgkmcnt only), B frags loaded global->reg from the L2-resident weight
// matrix (vmcnt only) -- ZERO barriers in the main loop, so the compiler can
// software-pipeline B loads across K-steps and waves slip independently.
// Waves split the 128-col tile 4 ways (64 rows x 32 cols each, acc[4][2]) so
// no B fragment is read twice within a block. 3 blocks/CU (LDS-capped).
template <int MODE>
__global__ __launch_bounds__(256) void gemm_kernel(
    const bf16* __restrict__ A, const bf16* __restrict__ Bt,
    bf16* __restrict__ qb, bf16* __restrict__ kb, bf16* __restrict__ vb,
    void* __restrict__ outp, const void* __restrict__ bias,
    int r_off, const int* __restrict__ flag) {
  constexpr int K = 384;
  constexpr int NT = (MODE == 0) ? 9 : 3;  // 128-col tiles
  __shared__ bf16 Ash[12][64 * 32];        // [K-chunk][row][col], 48 KB
  const int tid = threadIdx.x;
  const int lane = tid & 63;
  const int wave = tid >> 6;
  const int l15 = lane & 15, quad = lane >> 4;
  const int m0 = blockIdx.x * 64;

  // staging lane map (per 16-row group): row = lane>>2, slot = lane&3,
  // source col-rotation sc pairs with read-rotation fc (conflict-free).
  const int rl = lane >> 2;
  const int slot = lane & 3;
  const int sc = (slot - (lane >> 3)) & 3;

  // stage the whole 64x384 panel: wave w stages rows w*16..w*16+15 of each
  // 32-col K-chunk (one gload16 per chunk). All 12 issued back-to-back.
  const bf16* Ag = A + (size_t)(m0 + wave * 16 + rl) * K + sc * 8;
#pragma unroll
  for (int kt = 0; kt < 12; ++kt) gload16(Ag + kt * 32, &Ash[kt][wave * 512]);
  __syncthreads();  // the only barrier

  const int fc = ((quad + (l15 >> 1)) & 3) * 8;
  const f32x4 z4 = {0.f, 0.f, 0.f, 0.f};

  for (int nt = 0; nt < NT; ++nt) {
    f32x4 acc[4][2];
#pragma unroll
    for (int i = 0; i < 4; ++i)
#pragma unroll
      for (int j = 0; j < 2; ++j) acc[i][j] = z4;

    // B frag: n = l15 (col within 16-group), k = quad*8 -- direct from L2.
    const bf16* Bg = Bt + (size_t)(nt * 128 + wave * 32 + l15) * K + quad * 8;
#pragma unroll
    for (int kt = 0; kt < 12; ++kt) {
      s16x8 af[4], bfr[2];
#pragma unroll
      for (int i = 0; i < 4; ++i)
        af[i] = *(const s16x8*)(&Ash[kt][(i * 16 + l15) * 32 + fc]);
#pragma unroll
      for (int j = 0; j < 2; ++j)
        bfr[j] = *(const s16x8*)(Bg + (size_t)j * 16 * K + kt * 32);
#pragma unroll
      for (int i = 0; i < 4; ++i)
#pragma unroll
        for (int j = 0; j < 2; ++j) acc[i][j] = MFMA16(af[i], bfr[j], acc[i][j]);
    }

    if (MODE == 0) {
      const int sel = nt / 3;  // 0->Q, 1->K, 2->V
      bf16* dst = (sel == 0) ? qb : ((sel == 1) ? kb : vb);
#pragma unroll
      for (int j = 0; j < 2; ++j) {
        int n_g = nt * 128 + wave * 32 + j * 16 + l15;
        int c = n_g - sel * 384;
        int h = c >> 6, d = c & 63;
#pragma unroll
        for (int i = 0; i < 4; ++i) {
#pragma unroll
          for (int r = 0; r < 4; ++r) {
            int m_loc = m0 + i * 16 + quad * 4 + r;
            int b = m_loc >> 8, t = m_loc & 255;
            bf16 bv = __float2bfloat16(acc[i][j][r]);
            int bh = b * 6 + h;
            if (sel < 2) {
              dst[(size_t)bh * 16384 + t * 64 + d] = bv;   // [b,h,t,d]
            } else {
              // V^T [b,h,d,t'] with per-32-chunk key permutation so the attn
              // PV A-fragment is one contiguous 16B load per lane.
              int rr = t & 31;
              int pos = (((rr & 15) >> 2) << 3) | (rr & 3) | ((rr >> 4) << 2);
              int tt = (t & ~31) | pos;
              dst[(size_t)bh * 16384 + d * 256 + tt] = bv;
            }
          }
        }
      }
    } else {
      const int f32io = *flag;
#pragma unroll
      for (int j = 0; j < 2; ++j) {
        int n_g = nt * 128 + wave * 32 + j * 16 + l15;
        float bsv = f32io ? ((const float*)bias)[n_g]
                          : __bfloat162float(((const bf16*)bias)[n_g]);
#pragma unroll
        for (int i = 0; i < 4; ++i) {
#pragma unroll
          for (int r = 0; r < 4; ++r) {
            int m_loc = m0 + i * 16 + quad * 4 + r;
            size_t o = (size_t)(r_off + m_loc) * 384 + n_g;
            float val = acc[i][j][r] + bsv;
            if (f32io)
              ((float*)outp)[o] = val;
            else
              ((bf16*)outp)[o] = __float2bfloat16(val);
          }
        }
      }
    }
  }
}

// ---------------- causal attention: zero-LDS, paired chains, deep prefetch --
// grid: nb*12 blocks (bh, pair p); wave w owns TWO 16-row q-tiles of head bh:
//   jA = p*4+w (tiles 0..7) and jB = 15-jA (tiles 8..15).
// Total 32-key chunks per wave = ktA+ktB = 9 for every wave (balanced), and
// the two chains share K/V loads + interleave for ILP. Register-P trick:
// packed S output IS the PV B-fragment under key-permutation pi; V^T is
// stored pre-permuted by the gemm so vf is one s16x8 per dt.
// Pipeline: K ring 3 bufs (2 chunks ahead), V 2 bufs (1 ahead). No LDS.
__global__ __launch_bounds__(256, 3) void attn_kernel(const bf16* __restrict__ Q,
                                                      const bf16* __restrict__ Kb,
                                                      const bf16* __restrict__ Vt,
                                                      bf16* __restrict__ attn_out) {
  const int tid = threadIdx.x;
  const int lane = tid & 63;
  const int wave = tid >> 6;
  const int l15 = lane & 15, quad = lane >> 4;
  const int nblk = gridDim.x;
  int blk = blockIdx.x;
  if ((nblk & 7) == 0)  // bijective XCD swizzle (both blocks of a head -> same XCD L2)
    blk = (blockIdx.x & 7) * (nblk >> 3) + (blockIdx.x >> 3);
  const int p = blk & 1;
  const int bh = blk >> 1;
  const int jA = p * 4 + wave;   // light chain: tiles 0..7
  const int jB = 15 - jA;        // heavy chain: tiles 8..15
  const size_t base = (size_t)bh * 16384;
  const int q0A = jA * 16, q0B = jB * 16;

  // Q fragments (B-operand: n = l15 = q-row, k = quad*8+j = d)
  s16x8 qA0 = *(const s16x8*)(&Q[base + (q0A + l15) * 64 + quad * 8]);
  s16x8 qA1 = *(const s16x8*)(&Q[base + (q0A + l15) * 64 + 32 + quad * 8]);
  s16x8 qB0 = *(const s16x8*)(&Q[base + (q0B + l15) * 64 + quad * 8]);
  s16x8 qB1 = *(const s16x8*)(&Q[base + (q0B + l15) * 64 + 32 + quad * 8]);

  const int ktA = (jA + 2) >> 1;   // 1..4 chunks
  const int ktB = (jB + 2) >> 1;   // 4..8 chunks (>= ktA)
  const int tqA = q0A + l15, tqB = q0B + l15;
  const f32x4 z4 = {0.f, 0.f, 0.f, 0.f};

  const bf16* Kp = Kb + base + (size_t)l15 * 64 + quad * 8;
  const bf16* Vp = Vt + base + (size_t)l15 * 256 + quad * 8;

  typedef union { s16x8 v; uint32_t w[4]; } pf_t;

  // K ring (3 bufs, 2 ahead): [buf][hf*2 + d-half]; V ring (2 bufs, 1 ahead)
  s16x8 kf[3][4];
  s16x8 vf[2][4];
#pragma unroll
  for (int i = 0; i < 4; ++i) {
    kf[0][i] = *(const s16x8*)(Kp + (size_t)((i >> 1) * 16) * 64 + (i & 1) * 32);
    kf[1][i] = *(const s16x8*)(Kp + (size_t)(32 + (i >> 1) * 16) * 64 + (i & 1) * 32);
  }
#pragma unroll
  for (int dt = 0; dt < 4; ++dt) vf[0][dt] = *(const s16x8*)(Vp + (size_t)dt * 4096);

  f32x4 ofA[4], ofB[4];
#pragma unroll
  for (int dt = 0; dt < 4; ++dt) { ofA[dt] = z4; ofB[dt] = z4; }
  float rsA = 0.f, rsB = 0.f;

#pragma unroll
  for (int t = 0; t < 8; ++t) {
    if (t < ktB) {  // wave-uniform
      // prefetch K[t+2], V[t+1]
      if (t + 2 < ktB) {
        const bf16* Kn = Kp + (size_t)(t + 2) * 32 * 64;
#pragma unroll
        for (int i = 0; i < 4; ++i)
          kf[(t + 2) % 3][i] = *(const s16x8*)(Kn + (size_t)((i >> 1) * 16) * 64 + (i & 1) * 32);
      }
      if (t + 1 < ktB) {
#pragma unroll
        for (int dt = 0; dt < 4; ++dt)
          vf[(t + 1) & 1][dt] = *(const s16x8*)(Vp + (size_t)dt * 4096 + (t + 1) * 32);
      }
      // ---- chain B (always active while t < ktB) ----
      pf_t pfB;
#pragma unroll
      for (int hf = 0; hf < 2; ++hf) {
        const int nt = 2 * t + hf;
        if (nt <= jB) {  // wave-uniform
          f32x4 s = MFMA16(kf[t % 3][hf * 2 + 0], qB0, z4);
          s = MFMA16(kf[t % 3][hf * 2 + 1], qB1, s);
          const int tk0 = nt * 16 + quad * 4;
          float p0 = (tk0 + 0 <= tqB) ? __expf(s[0] * 0.125f) : 0.f;
          float p1 = (tk0 + 1 <= tqB) ? __expf(s[1] * 0.125f) : 0.f;
          float p2 = (tk0 + 2 <= tqB) ? __expf(s[2] * 0.125f) : 0.f;
          float p3 = (tk0 + 3 <= tqB) ? __expf(s[3] * 0.125f) : 0.f;
          rsB += (p0 + p1) + (p2 + p3);
          union { bf16 hh[2]; uint32_t u; } w0, w1;
          w0.hh[0] = __float2bfloat16(p0); w0.hh[1] = __float2bfloat16(p1);
          w1.hh[0] = __float2bfloat16(p2); w1.hh[1] = __float2bfloat16(p3);
          pfB.w[hf * 2 + 0] = w0.u;
          pfB.w[hf * 2 + 1] = w1.u;
        } else {
          pfB.w[hf * 2 + 0] = 0u;
          pfB.w[hf * 2 + 1] = 0u;
        }
      }
      // ---- chain A (first ktA chunks) ----
      if (t < ktA) {  // wave-uniform
        pf_t pfA;
#pragma unroll
        for (int hf = 0; hf < 2; ++hf) {
          const int nt = 2 * t + hf;
          if (nt <= jA) {  // wave-uniform
            f32x4 s = MFMA16(kf[t % 3][hf * 2 + 0], qA0, z4);
            s = MFMA16(kf[t % 3][hf * 2 + 1], qA1, s);
            const int tk0 = nt * 16 + quad * 4;
            float p0 = (tk0 + 0 <= tqA) ? __expf(s[0] * 0.125f) : 0.f;
            float p1 = (tk0 + 1 <= tqA) ? __expf(s[1] * 0.125f) : 0.f;
            float p2 = (tk0 + 2 <= tqA) ? __expf(s[2] * 0.125f) : 0.f;
            float p3 = (tk0 + 3 <= tqA) ? __expf(s[3] * 0.125f) : 0.f;
            rsA += (p0 + p1) + (p2 + p3);
            union { bf16 hh[2]; uint32_t u; } w0, w1;
            w0.hh[0] = __float2bfloat16(p0); w0.hh[1] = __float2bfloat16(p1);
            w1.hh[0] = __float2bfloat16(p2); w1.hh[1] = __float2bfloat16(p3);
            pfA.w[hf * 2 + 0] = w0.u;
            pfA.w[hf * 2 + 1] = w1.u;
          } else {
            pfA.w[hf * 2 + 0] = 0u;
            pfA.w[hf * 2 + 1] = 0u;
          }
        }
#pragma unroll
        for (int dt = 0; dt < 4; ++dt) ofA[dt] = MFMA16(vf[t & 1][dt], pfA.v, ofA[dt]);
      }
#pragma unroll
      for (int dt = 0; dt < 4; ++dt) ofB[dt] = MFMA16(vf[t & 1][dt], pfB.v, ofB[dt]);
    }
  }

  rsA += __shfl_xor(rsA, 16);
  rsA += __shfl_xor(rsA, 32);
  rsB += __shfl_xor(rsB, 16);
  rsB += __shfl_xor(rsB, 32);
  const float invA = 1.0f / rsA;
  const float invB = 1.0f / rsB;

  const int b = bh / 6;
  const int h = bh - b * 6;
  const size_t orowA = (size_t)(b * 256 + q0A + l15) * 384 + h * 64;
  const size_t orowB = (size_t)(b * 256 + q0B + l15) * 384 + h * 64;
#pragma unroll
  for (int dt = 0; dt < 4; ++dt) {
    union { bf16 h4[4]; uint2 u; } oa, ob;
#pragma unroll
    for (int r = 0; r < 4; ++r) {
      oa.h4[r] = __float2bfloat16(ofA[dt][r] * invA);
      ob.h4[r] = __float2bfloat16(ofB[dt][r] * invB);
    }
    *(uint2*)(&attn_out[orowA + dt * 16 + quad * 4]) = oa.u;
    *(uint2*)(&attn_out[orowB + dt * 16 + quad * 4]) = ob.u;
  }
}

// ---------------- launcher ----------------
extern "C" void kernel_launch(void* const* d_in, const int* in_sizes, int n_in,
                              void* d_out, int out_size, void* d_ws, size_t ws_size,
                              hipStream_t stream) {
  const void* x = d_in[0];       // [256,256,384]  fp32 or bf16 (detected)
  const void* Wqkv = d_in[1];    // [384,1152]
  const void* Wproj = d_in[2];   // [384,384]
  const void* bproj = d_in[3];   // [384]

  char* ws = (char*)d_ws;
  int* flag = (int*)ws;                ws += 256;
  bf16* Wt_qkv = (bf16*)ws;            ws += (size_t)1152 * 384 * 2;
  bf16* Wt_proj = (bf16*)ws;           ws += (size_t)384 * 384 * 2;

  const size_t per_batch = (size_t)5 * 98304 * 2;  // xb,q,k,vt,attn per batch
  size_t used = (size_t)(ws - (char*)d_ws);
  size_t remain = (ws_size > used) ? (ws_size - used) : 0;
  int NB = (int)(remain / per_batch);
  if (NB > 256) NB = 256;
  if (NB < 1) NB = 1;

  bf16* xb_buf = (bf16*)ws;
  bf16* q_buf = xb_buf + (size_t)NB * 98304;
  bf16* k_buf = q_buf + (size_t)NB * 98304;
  bf16* vt_buf = k_buf + (size_t)NB * 98304;
  bf16* attn_buf = vt_buf + (size_t)NB * 98304;

  detect_kernel<<<1, 256, 0, stream>>>(x, flag);
  transpose_kernel<<<(384 * 1152 + 255) / 256, 256, 0, stream>>>(Wqkv, Wt_qkv, 384, 1152, flag);
  transpose_kernel<<<(384 * 384 + 255) / 256, 256, 0, stream>>>(Wproj, Wt_proj, 384, 384, flag);

  for (int b0 = 0; b0 < 256; b0 += NB) {
    int nb = (256 - b0 < NB) ? (256 - b0) : NB;
    int r_off = b0 * 256;
    convert_kernel<<<nb * 48, 256, 0, stream>>>(x, xb_buf, (size_t)r_off * 384, flag);
    gemm_kernel<0><<<dim3(4 * nb), 256, 0, stream>>>(
        xb_buf, Wt_qkv, q_buf, k_buf, vt_buf, nullptr, nullptr, 0, flag);
    attn_kernel<<<nb * 12, 256, 0, stream>>>(q_buf, k_buf, vt_buf, attn_buf);
    gemm_kernel<1><<<dim3(4 * nb), 256, 0, stream>>>(
        attn_buf, Wt_proj, nullptr, nullptr, nullptr, d_out, bproj, r_off, flag);
  }
}

// Round 9
// 453.074 us; speedup vs baseline: 1.1346x; 1.1346x over previous
//
#include <hip/hip_runtime.h>
#include <hip/hip_bf16.h>
#include <stdint.h>

typedef __hip_bfloat16 bf16;
using f32x4 = __attribute__((ext_vector_type(4))) float;
using s16x8 = __attribute__((ext_vector_type(8))) short;

#define MFMA16(A_, B_, C_) __builtin_amdgcn_mfma_f32_16x16x32_bf16((A_), (B_), (C_), 0, 0, 0)

__device__ __forceinline__ void gload16(const void* g, void* l) {
  __builtin_amdgcn_global_load_lds((const __attribute__((address_space(1))) void*)g,
                                   (__attribute__((address_space(3))) void*)l, 16, 0, 0);
}

// ---------------- dtype detector ----------------
// flag=1 -> inputs/outputs fp32; flag=0 -> bf16.
__global__ __launch_bounds__(256) void detect_kernel(const void* __restrict__ x,
                                                     int* __restrict__ flag) {
  __shared__ int cnt;
  if (threadIdx.x == 0) cnt = 0;
  __syncthreads();
  const uint32_t* w = (const uint32_t*)x;
  int local = 0;
#pragma unroll
  for (int i = 0; i < 8; ++i) {
    uint32_t v = w[threadIdx.x * 8 + i];
    uint32_t e = (v >> 7) & 0xFF;
    if (e >= 110 && e <= 135) local++;
  }
  atomicAdd(&cnt, local);
  __syncthreads();
  if (threadIdx.x == 0) *flag = (cnt < 1024) ? 1 : 0;
}

// ---------------- x chunk -> bf16 (vectorized) ----------------
__global__ __launch_bounds__(256) void convert_kernel(const void* __restrict__ x,
                                                      bf16* __restrict__ xb,
                                                      size_t elem_off,
                                                      const int* __restrict__ flag) {
  size_t i = ((size_t)blockIdx.x * 256 + threadIdx.x) * 8;
  if (*flag) {
    const float* xf = (const float*)x + elem_off + i;
    float4 a = ((const float4*)xf)[0];
    float4 b = ((const float4*)xf)[1];
    union { bf16 h[8]; uint4 u; } o;
    o.h[0] = __float2bfloat16(a.x); o.h[1] = __float2bfloat16(a.y);
    o.h[2] = __float2bfloat16(a.z); o.h[3] = __float2bfloat16(a.w);
    o.h[4] = __float2bfloat16(b.x); o.h[5] = __float2bfloat16(b.y);
    o.h[6] = __float2bfloat16(b.z); o.h[7] = __float2bfloat16(b.w);
    *(uint4*)(&xb[i]) = o.u;
  } else {
    *(uint4*)(&xb[i]) = *(const uint4*)((const bf16*)x + elem_off + i);
  }
}

// ---------------- transpose: Wt[n][k] = W[k][n], W is [K][N] ----------------
__global__ __launch_bounds__(256) void transpose_kernel(const void* __restrict__ W,
                                                        bf16* __restrict__ Wt,
                                                        int K, int N,
                                                        const int* __restrict__ flag) {
  int idx = blockIdx.x * 256 + threadIdx.x;
  if (idx >= K * N) return;
  int n = idx / K;
  int k = idx - n * K;
  if (*flag)
    Wt[idx] = __float2bfloat16(((const float*)W)[k * N + n]);
  else
    Wt[idx] = ((const bf16*)W)[k * N + n];
}

// ---------------- GEMM: C[M][N] = A[M][384] * Bt[N][384]^T ----------------
// Round-9: round-7's proven double-buffered barrier skeleton, M-tile scaled
// 128->256 (tile 256x128, 4 waves each 64 rows x 128 cols, acc[4][8]).
// 32 MFMA/wave/K-step amortizes the per-step vmcnt(0)+barrier 2x; B-tile
// reuse doubles; staging bytes per FLOP halve (6 gload16 / step / thread).
// LDS 48 KB (A 2x16K + B 2x8K) -> 3 blocks/CU; launch_bounds(256,2) caps
// VGPR at 256 (est ~190, no spill). Chunked bijective XCD swizzle kept.
template <int MODE>
__global__ __launch_bounds__(256, 2) void gemm_kernel(
    const bf16* __restrict__ A, const bf16* __restrict__ Bt,
    bf16* __restrict__ qb, bf16* __restrict__ kb, bf16* __restrict__ vb,
    void* __restrict__ outp, const void* __restrict__ bias,
    int r_off, const int* __restrict__ flag) {
  constexpr int K = 384;
  __shared__ bf16 Ash[2][256 * 32];
  __shared__ bf16 Bsh[2][128 * 32];
  const int tid = threadIdx.x;
  const int lane = tid & 63;
  const int wave = tid >> 6;
  const int l15 = lane & 15, quad = lane >> 4;

  // ---- chunked XCD swizzle on linearized (x-fastest) block index ----
  const int nlin = gridDim.x * gridDim.y;
  const int orig = blockIdx.y * gridDim.x + blockIdx.x;
  const int xcd = orig & 7;
  const int q8 = nlin >> 3, r8 = nlin & 7;
  const int lin = (xcd < r8 ? xcd * (q8 + 1) : r8 * (q8 + 1) + (xcd - r8) * q8) + (orig >> 3);
  const int bx = lin % gridDim.x;
  const int by = lin / gridDim.x;
  const int n0 = bx * 128, m0 = by * 256;

  // staging lane map (per 16-row group): row = lane>>2, slot = lane&3,
  // source col-rotation sc pairs with read-rotation fc (conflict-free).
  const int rl = lane >> 2;
  const int slot = lane & 3;
  const int sc = (slot - (lane >> 3)) & 3;

  const bf16* Ag = A + (size_t)(m0 + wave * 16 + rl) * K + sc * 8;
  const bf16* Bg = Bt + (size_t)(n0 + wave * 16 + rl) * K + sc * 8;

  // stage one 32-col K-chunk of the 256-row A tile + 128-row B tile
  auto stage = [&](int buf, int k0) {
#pragma unroll
    for (int qd = 0; qd < 4; ++qd)
      gload16(Ag + (size_t)qd * 64 * K + k0, &Ash[buf][(qd * 64 + wave * 16) * 32]);
#pragma unroll
    for (int h = 0; h < 2; ++h)
      gload16(Bg + (size_t)h * 64 * K + k0, &Bsh[buf][(h * 64 + wave * 16) * 32]);
  };

  const int fc = ((quad + (l15 >> 1)) & 3) * 8;
  const f32x4 z4 = {0.f, 0.f, 0.f, 0.f};
  f32x4 acc[4][8];
#pragma unroll
  for (int i = 0; i < 4; ++i)
#pragma unroll
    for (int j = 0; j < 8; ++j) acc[i][j] = z4;

  stage(0, 0);
  __syncthreads();
  int cur = 0;
  for (int kt = 0; kt < 12; ++kt) {
    if (kt < 11) stage(cur ^ 1, (kt + 1) * 32);  // prefetch next tile
    s16x8 af[4], bfr[8];
#pragma unroll
    for (int i = 0; i < 4; ++i)
      af[i] = *(const s16x8*)(&Ash[cur][(wave * 64 + i * 16 + l15) * 32 + fc]);
#pragma unroll
    for (int j = 0; j < 8; ++j)
      bfr[j] = *(const s16x8*)(&Bsh[cur][(j * 16 + l15) * 32 + fc]);
#pragma unroll
    for (int i = 0; i < 4; ++i)
#pragma unroll
      for (int j = 0; j < 8; ++j) acc[i][j] = MFMA16(af[i], bfr[j], acc[i][j]);
    __syncthreads();
    cur ^= 1;
  }

  if (MODE == 0) {
    const int sel = bx / 3;  // 0->Q, 1->K, 2->V
    bf16* dst = (sel == 0) ? qb : ((sel == 1) ? kb : vb);
#pragma unroll
    for (int j = 0; j < 8; ++j) {
      int n_g = n0 + j * 16 + l15;
      int c = n_g - sel * 384;
      int h = c >> 6, d = c & 63;
#pragma unroll
      for (int i = 0; i < 4; ++i) {
#pragma unroll
        for (int r = 0; r < 4; ++r) {
          int m_loc = m0 + wave * 64 + i * 16 + quad * 4 + r;
          int b = m_loc >> 8, t = m_loc & 255;
          bf16 bv = __float2bfloat16(acc[i][j][r]);
          int bh = b * 6 + h;
          if (sel < 2) {
            dst[(size_t)bh * 16384 + t * 64 + d] = bv;   // [b,h,t,d]
          } else {
            // V^T [b,h,d,t'] with per-32-chunk key permutation so the attn
            // PV A-fragment is one contiguous 16B load per lane.
            int rr = t & 31;
            int pos = (((rr & 15) >> 2) << 3) | (rr & 3) | ((rr >> 4) << 2);
            int tt = (t & ~31) | pos;
            dst[(size_t)bh * 16384 + d * 256 + tt] = bv;
          }
        }
      }
    }
  } else {
    const int f32io = *flag;
#pragma unroll
    for (int j = 0; j < 8; ++j) {
      int n_g = n0 + j * 16 + l15;
      float bsv = f32io ? ((const float*)bias)[n_g]
                        : __bfloat162float(((const bf16*)bias)[n_g]);
#pragma unroll
      for (int i = 0; i < 4; ++i) {
#pragma unroll
        for (int r = 0; r < 4; ++r) {
          int m_loc = m0 + wave * 64 + i * 16 + quad * 4 + r;
          size_t o = (size_t)(r_off + m_loc) * 384 + n_g;
          float val = acc[i][j][r] + bsv;
          if (f32io)
            ((float*)outp)[o] = val;
          else
            ((bf16*)outp)[o] = __float2bfloat16(val);
        }
      }
    }
  }
}

// ---------------- causal attention: zero-LDS, paired chains, deep prefetch --
// grid: nb*12 blocks (bh, pair p); wave w owns TWO 16-row q-tiles of head bh:
//   jA = p*4+w (tiles 0..7) and jB = 15-jA (tiles 8..15).
// Total 32-key chunks per wave = ktA+ktB = 9 for every wave (balanced), and
// the two chains share K/V loads + interleave for ILP. Register-P trick:
// packed S output IS the PV B-fragment under key-permutation pi; V^T is
// stored pre-permuted by the gemm so vf is one s16x8 per dt.
// Pipeline: K ring 3 bufs (2 chunks ahead), V 2 bufs (1 ahead). No LDS.
__global__ __launch_bounds__(256, 3) void attn_kernel(const bf16* __restrict__ Q,
                                                      const bf16* __restrict__ Kb,
                                                      const bf16* __restrict__ Vt,
                                                      bf16* __restrict__ attn_out) {
  const int tid = threadIdx.x;
  const int lane = tid & 63;
  const int wave = tid >> 6;
  const int l15 = lane & 15, quad = lane >> 4;
  const int nblk = gridDim.x;
  int blk = blockIdx.x;
  if ((nblk & 7) == 0)  // bijective XCD swizzle (both blocks of a head -> same XCD L2)
    blk = (blockIdx.x & 7) * (nblk >> 3) + (blockIdx.x >> 3);
  const int p = blk & 1;
  const int bh = blk >> 1;
  const int jA = p * 4 + wave;   // light chain: tiles 0..7
  const int jB = 15 - jA;        // heavy chain: tiles 8..15
  const size_t base = (size_t)bh * 16384;
  const int q0A = jA * 16, q0B = jB * 16;

  // Q fragments (B-operand: n = l15 = q-row, k = quad*8+j = d)
  s16x8 qA0 = *(const s16x8*)(&Q[base + (q0A + l15) * 64 + quad * 8]);
  s16x8 qA1 = *(const s16x8*)(&Q[base + (q0A + l15) * 64 + 32 + quad * 8]);
  s16x8 qB0 = *(const s16x8*)(&Q[base + (q0B + l15) * 64 + quad * 8]);
  s16x8 qB1 = *(const s16x8*)(&Q[base + (q0B + l15) * 64 + 32 + quad * 8]);

  const int ktA = (jA + 2) >> 1;   // 1..4 chunks
  const int ktB = (jB + 2) >> 1;   // 4..8 chunks (>= ktA)
  const int tqA = q0A + l15, tqB = q0B + l15;
  const f32x4 z4 = {0.f, 0.f, 0.f, 0.f};

  const bf16* Kp = Kb + base + (size_t)l15 * 64 + quad * 8;
  const bf16* Vp = Vt + base + (size_t)l15 * 256 + quad * 8;

  typedef union { s16x8 v; uint32_t w[4]; } pf_t;

  // K ring (3 bufs, 2 ahead): [buf][hf*2 + d-half]; V ring (2 bufs, 1 ahead)
  s16x8 kf[3][4];
  s16x8 vf[2][4];
#pragma unroll
  for (int i = 0; i < 4; ++i) {
    kf[0][i] = *(const s16x8*)(Kp + (size_t)((i >> 1) * 16) * 64 + (i & 1) * 32);
    kf[1][i] = *(const s16x8*)(Kp + (size_t)(32 + (i >> 1) * 16) * 64 + (i & 1) * 32);
  }
#pragma unroll
  for (int dt = 0; dt < 4; ++dt) vf[0][dt] = *(const s16x8*)(Vp + (size_t)dt * 4096);

  f32x4 ofA[4], ofB[4];
#pragma unroll
  for (int dt = 0; dt < 4; ++dt) { ofA[dt] = z4; ofB[dt] = z4; }
  float rsA = 0.f, rsB = 0.f;

#pragma unroll
  for (int t = 0; t < 8; ++t) {
    if (t < ktB) {  // wave-uniform
      // prefetch K[t+2], V[t+1]
      if (t + 2 < ktB) {
        const bf16* Kn = Kp + (size_t)(t + 2) * 32 * 64;
#pragma unroll
        for (int i = 0; i < 4; ++i)
          kf[(t + 2) % 3][i] = *(const s16x8*)(Kn + (size_t)((i >> 1) * 16) * 64 + (i & 1) * 32);
      }
      if (t + 1 < ktB) {
#pragma unroll
        for (int dt = 0; dt < 4; ++dt)
          vf[(t + 1) & 1][dt] = *(const s16x8*)(Vp + (size_t)dt * 4096 + (t + 1) * 32);
      }
      // ---- chain B (always active while t < ktB) ----
      pf_t pfB;
#pragma unroll
      for (int hf = 0; hf < 2; ++hf) {
        const int nt = 2 * t + hf;
        if (nt <= jB) {  // wave-uniform
          f32x4 s = MFMA16(kf[t % 3][hf * 2 + 0], qB0, z4);
          s = MFMA16(kf[t % 3][hf * 2 + 1], qB1, s);
          const int tk0 = nt * 16 + quad * 4;
          float p0 = (tk0 + 0 <= tqB) ? __expf(s[0] * 0.125f) : 0.f;
          float p1 = (tk0 + 1 <= tqB) ? __expf(s[1] * 0.125f) : 0.f;
          float p2 = (tk0 + 2 <= tqB) ? __expf(s[2] * 0.125f) : 0.f;
          float p3 = (tk0 + 3 <= tqB) ? __expf(s[3] * 0.125f) : 0.f;
          rsB += (p0 + p1) + (p2 + p3);
          union { bf16 hh[2]; uint32_t u; } w0, w1;
          w0.hh[0] = __float2bfloat16(p0); w0.hh[1] = __float2bfloat16(p1);
          w1.hh[0] = __float2bfloat16(p2); w1.hh[1] = __float2bfloat16(p3);
          pfB.w[hf * 2 + 0] = w0.u;
          pfB.w[hf * 2 + 1] = w1.u;
        } else {
          pfB.w[hf * 2 + 0] = 0u;
          pfB.w[hf * 2 + 1] = 0u;
        }
      }
      // ---- chain A (first ktA chunks) ----
      if (t < ktA) {  // wave-uniform
        pf_t pfA;
#pragma unroll
        for (int hf = 0; hf < 2; ++hf) {
          const int nt = 2 * t + hf;
          if (nt <= jA) {  // wave-uniform
            f32x4 s = MFMA16(kf[t % 3][hf * 2 + 0], qA0, z4);
            s = MFMA16(kf[t % 3][hf * 2 + 1], qA1, s);
            const int tk0 = nt * 16 + quad * 4;
            float p0 = (tk0 + 0 <= tqA) ? __expf(s[0] * 0.125f) : 0.f;
            float p1 = (tk0 + 1 <= tqA) ? __expf(s[1] * 0.125f) : 0.f;
            float p2 = (tk0 + 2 <= tqA) ? __expf(s[2] * 0.125f) : 0.f;
            float p3 = (tk0 + 3 <= tqA) ? __expf(s[3] * 0.125f) : 0.f;
            rsA += (p0 + p1) + (p2 + p3);
            union { bf16 hh[2]; uint32_t u; } w0, w1;
            w0.hh[0] = __float2bfloat16(p0); w0.hh[1] = __float2bfloat16(p1);
            w1.hh[0] = __float2bfloat16(p2); w1.hh[1] = __float2bfloat16(p3);
            pfA.w[hf * 2 + 0] = w0.u;
            pfA.w[hf * 2 + 1] = w1.u;
          } else {
            pfA.w[hf * 2 + 0] = 0u;
            pfA.w[hf * 2 + 1] = 0u;
          }
        }
#pragma unroll
        for (int dt = 0; dt < 4; ++dt) ofA[dt] = MFMA16(vf[t & 1][dt], pfA.v, ofA[dt]);
      }
#pragma unroll
      for (int dt = 0; dt < 4; ++dt) ofB[dt] = MFMA16(vf[t & 1][dt], pfB.v, ofB[dt]);
    }
  }

  rsA += __shfl_xor(rsA, 16);
  rsA += __shfl_xor(rsA, 32);
  rsB += __shfl_xor(rsB, 16);
  rsB += __shfl_xor(rsB, 32);
  const float invA = 1.0f / rsA;
  const float invB = 1.0f / rsB;

  const int b = bh / 6;
  const int h = bh - b * 6;
  const size_t orowA = (size_t)(b * 256 + q0A + l15) * 384 + h * 64;
  const size_t orowB = (size_t)(b * 256 + q0B + l15) * 384 + h * 64;
#pragma unroll
  for (int dt = 0; dt < 4; ++dt) {
    union { bf16 h4[4]; uint2 u; } oa, ob;
#pragma unroll
    for (int r = 0; r < 4; ++r) {
      oa.h4[r] = __float2bfloat16(ofA[dt][r] * invA);
      ob.h4[r] = __float2bfloat16(ofB[dt][r] * invB);
    }
    *(uint2*)(&attn_out[orowA + dt * 16 + quad * 4]) = oa.u;
    *(uint2*)(&attn_out[orowB + dt * 16 + quad * 4]) = ob.u;
  }
}

// ---------------- launcher ----------------
extern "C" void kernel_launch(void* const* d_in, const int* in_sizes, int n_in,
                              void* d_out, int out_size, void* d_ws, size_t ws_size,
                              hipStream_t stream) {
  const void* x = d_in[0];       // [256,256,384]  fp32 or bf16 (detected)
  const void* Wqkv = d_in[1];    // [384,1152]
  const void* Wproj = d_in[2];   // [384,384]
  const void* bproj = d_in[3];   // [384]

  char* ws = (char*)d_ws;
  int* flag = (int*)ws;                ws += 256;
  bf16* Wt_qkv = (bf16*)ws;            ws += (size_t)1152 * 384 * 2;
  bf16* Wt_proj = (bf16*)ws;           ws += (size_t)384 * 384 * 2;

  const size_t per_batch = (size_t)5 * 98304 * 2;  // xb,q,k,vt,attn per batch
  size_t used = (size_t)(ws - (char*)d_ws);
  size_t remain = (ws_size > used) ? (ws_size - used) : 0;
  int NB = (int)(remain / per_batch);
  if (NB > 256) NB = 256;
  if (NB < 1) NB = 1;

  bf16* xb_buf = (bf16*)ws;
  bf16* q_buf = xb_buf + (size_t)NB * 98304;
  bf16* k_buf = q_buf + (size_t)NB * 98304;
  bf16* vt_buf = k_buf + (size_t)NB * 98304;
  bf16* attn_buf = vt_buf + (size_t)NB * 98304;

  detect_kernel<<<1, 256, 0, stream>>>(x, flag);
  transpose_kernel<<<(384 * 1152 + 255) / 256, 256, 0, stream>>>(Wqkv, Wt_qkv, 384, 1152, flag);
  transpose_kernel<<<(384 * 384 + 255) / 256, 256, 0, stream>>>(Wproj, Wt_proj, 384, 384, flag);

  for (int b0 = 0; b0 < 256; b0 += NB) {
    int nb = (256 - b0 < NB) ? (256 - b0) : NB;
    int r_off = b0 * 256;
    convert_kernel<<<nb * 48, 256, 0, stream>>>(x, xb_buf, (size_t)r_off * 384, flag);
    gemm_kernel<0><<<dim3(9, nb), 256, 0, stream>>>(
        xb_buf, Wt_qkv, q_buf, k_buf, vt_buf, nullptr, nullptr, 0, flag);
    attn_kernel<<<nb * 12, 256, 0, stream>>>(q_buf, k_buf, vt_buf, attn_buf);
    gemm_kernel<1><<<dim3(3, nb), 256, 0, stream>>>(
        attn_buf, Wt_proj, nullptr, nullptr, nullptr, d_out, bproj, r_off, flag);
  }
}

// Round 10
// 433.558 us; speedup vs baseline: 1.1856x; 1.0450x over previous
//
#include <hip/hip_runtime.h>
#include <hip/hip_bf16.h>
#include <stdint.h>

typedef __hip_bfloat16 bf16;
using f32x4 = __attribute__((ext_vector_type(4))) float;
using s16x8 = __attribute__((ext_vector_type(8))) short;

#define MFMA16(A_, B_, C_) __builtin_amdgcn_mfma_f32_16x16x32_bf16((A_), (B_), (C_), 0, 0, 0)

__device__ __forceinline__ void gload16(const void* g, void* l) {
  __builtin_amdgcn_global_load_lds((const __attribute__((address_space(1))) void*)g,
                                   (__attribute__((address_space(3))) void*)l, 16, 0, 0);
}

// ---------------- dtype detector ----------------
// flag=1 -> inputs/outputs fp32; flag=0 -> bf16.
__global__ __launch_bounds__(256) void detect_kernel(const void* __restrict__ x,
                                                     int* __restrict__ flag) {
  __shared__ int cnt;
  if (threadIdx.x == 0) cnt = 0;
  __syncthreads();
  const uint32_t* w = (const uint32_t*)x;
  int local = 0;
#pragma unroll
  for (int i = 0; i < 8; ++i) {
    uint32_t v = w[threadIdx.x * 8 + i];
    uint32_t e = (v >> 7) & 0xFF;
    if (e >= 110 && e <= 135) local++;
  }
  atomicAdd(&cnt, local);
  __syncthreads();
  if (threadIdx.x == 0) *flag = (cnt < 1024) ? 1 : 0;
}

// ---------------- x chunk -> bf16 (vectorized) ----------------
__global__ __launch_bounds__(256) void convert_kernel(const void* __restrict__ x,
                                                      bf16* __restrict__ xb,
                                                      size_t elem_off,
                                                      const int* __restrict__ flag) {
  size_t i = ((size_t)blockIdx.x * 256 + threadIdx.x) * 8;
  if (*flag) {
    const float* xf = (const float*)x + elem_off + i;
    float4 a = ((const float4*)xf)[0];
    float4 b = ((const float4*)xf)[1];
    union { bf16 h[8]; uint4 u; } o;
    o.h[0] = __float2bfloat16(a.x); o.h[1] = __float2bfloat16(a.y);
    o.h[2] = __float2bfloat16(a.z); o.h[3] = __float2bfloat16(a.w);
    o.h[4] = __float2bfloat16(b.x); o.h[5] = __float2bfloat16(b.y);
    o.h[6] = __float2bfloat16(b.z); o.h[7] = __float2bfloat16(b.w);
    *(uint4*)(&xb[i]) = o.u;
  } else {
    *(uint4*)(&xb[i]) = *(const uint4*)((const bf16*)x + elem_off + i);
  }
}

// ---------------- transpose: Wt[n][k] = W[k][n], W is [K][N] ----------------
__global__ __launch_bounds__(256) void transpose_kernel(const void* __restrict__ W,
                                                        bf16* __restrict__ Wt,
                                                        int K, int N,
                                                        const int* __restrict__ flag) {
  int idx = blockIdx.x * 256 + threadIdx.x;
  if (idx >= K * N) return;
  int n = idx / K;
  int k = idx - n * K;
  if (*flag)
    Wt[idx] = __float2bfloat16(((const float*)W)[k * N + n]);
  else
    Wt[idx] = ((const bf16*)W)[k * N + n];
}

// ---------------- GEMM: C[M][N] = A[M][384] * Bt[N][384]^T ----------------
// R10: R7's proven 128x128 double-buffered skeleton + VECTORIZED EPILOGUES.
// The R5-R9 plateau (~133-149us) was store-issue-bound: 75.5M scalar 2B
// stores ~= 123us at 1 VMEM/cyc/CU. Fix via fragment orientation:
//  - SWAP=true (Q/K, proj): compute C^T = MFMA(B,A); lane then holds 4
//    CONSECUTIVE n (=d / proj col) for fixed t -> one uint2/float4 store
//    per (i,j). 4x fewer, 4x wider.
//  - SWAP=false (V^T): lane holds 4 consecutive t; the key-permutation is
//    4-aligned-friendly (pos(t0+r)=pos(t0)+r), so 4 r-values are 4
//    consecutive tt -> one uint2 store.
// K-loop, staging, sc/fc swizzle, chunked XCD swizzle: unchanged from R7.
template <int MODE, bool SWAP>
__global__ __launch_bounds__(256) void gemm_kernel(
    const bf16* __restrict__ A, const bf16* __restrict__ Bt,
    bf16* __restrict__ qb, bf16* __restrict__ kb, bf16* __restrict__ vb,
    void* __restrict__ outp, const void* __restrict__ bias,
    int r_off, int bx_off, const int* __restrict__ flag) {
  constexpr int K = 384;
  __shared__ bf16 Ash[2][128 * 32];
  __shared__ bf16 Bsh[2][128 * 32];
  const int tid = threadIdx.x;
  const int lane = tid & 63;
  const int wave = tid >> 6;
  const int wm = wave & 1, wn = wave >> 1;
  const int l15 = lane & 15, quad = lane >> 4;

  // ---- chunked XCD swizzle on linearized (x-fastest) block index ----
  const int nlin = gridDim.x * gridDim.y;
  const int orig = blockIdx.y * gridDim.x + blockIdx.x;
  const int xcd = orig & 7;
  const int q8 = nlin >> 3, r8 = nlin & 7;
  const int lin = (xcd < r8 ? xcd * (q8 + 1) : r8 * (q8 + 1) + (xcd - r8) * q8) + (orig >> 3);
  const int bx = lin % gridDim.x;
  const int by = lin / gridDim.x;
  const int n0 = (bx + bx_off) * 128, m0 = by * 128;

  const int rl = lane >> 2;
  const int slot = lane & 3;
  const int sc = (slot - (lane >> 3)) & 3;
  const size_t lane_goff = (size_t)rl * K + sc * 8;

  const int arow0 = wave * 32;
  const bf16* Ag0 = A + (size_t)(m0 + arow0) * K + lane_goff;
  const bf16* Ag1 = Ag0 + (size_t)16 * K;
  const bf16* Bg0 = Bt + (size_t)(n0 + arow0) * K + lane_goff;
  const bf16* Bg1 = Bg0 + (size_t)16 * K;

  auto stage = [&](int buf, int k0) {
    gload16(Ag0 + k0, &Ash[buf][arow0 * 32]);
    gload16(Ag1 + k0, &Ash[buf][(arow0 + 16) * 32]);
    gload16(Bg0 + k0, &Bsh[buf][arow0 * 32]);
    gload16(Bg1 + k0, &Bsh[buf][(arow0 + 16) * 32]);
  };

  const int fc = ((quad + (l15 >> 1)) & 3) * 8;

  const f32x4 z4 = {0.f, 0.f, 0.f, 0.f};
  f32x4 acc[4][4];
#pragma unroll
  for (int i = 0; i < 4; ++i)
#pragma unroll
    for (int j = 0; j < 4; ++j) acc[i][j] = z4;

  stage(0, 0);
  __syncthreads();
  int cur = 0;
  for (int kt = 0; kt < 12; ++kt) {
    if (kt < 11) stage(cur ^ 1, (kt + 1) * 32);  // prefetch next tile
    s16x8 af[4], bfr[4];
#pragma unroll
    for (int i = 0; i < 4; ++i) {
      af[i] = *(const s16x8*)(&Ash[cur][(wm * 64 + i * 16 + l15) * 32 + fc]);
      bfr[i] = *(const s16x8*)(&Bsh[cur][(wn * 64 + i * 16 + l15) * 32 + fc]);
    }
#pragma unroll
    for (int i = 0; i < 4; ++i)
#pragma unroll
      for (int j = 0; j < 4; ++j) {
        if constexpr (SWAP)
          acc[i][j] = MFMA16(bfr[j], af[i], acc[i][j]);  // C^T: lane col=m, rows=n
        else
          acc[i][j] = MFMA16(af[i], bfr[j], acc[i][j]);  // C: lane col=n, rows=m
      }
    __syncthreads();
    cur ^= 1;
  }

  const int mbase = m0 + wm * 64;
  const int nbase = n0 + wn * 64;
  if (MODE == 0) {
    if constexpr (SWAP) {
      // Q/K store: lane holds m = mbase+i*16+l15 (fixed), n = nbase+j*16+quad*4+r
      // -> 4 consecutive d within one head (4-aligned, never crosses d=64).
      const int sel = (bx + bx_off) / 3;  // 0->Q, 1->K
      bf16* dst = (sel == 0) ? qb : kb;
#pragma unroll
      for (int i = 0; i < 4; ++i) {
        int m_loc = mbase + i * 16 + l15;
        int b = m_loc >> 8, t = m_loc & 255;
#pragma unroll
        for (int j = 0; j < 4; ++j) {
          int c = nbase + j * 16 + quad * 4 - sel * 384;
          int h = c >> 6, d0 = c & 63;
          int bh = b * 6 + h;
          union { bf16 h4[4]; uint2 u; } o;
#pragma unroll
          for (int r = 0; r < 4; ++r) o.h4[r] = __float2bfloat16(acc[i][j][r]);
          *(uint2*)(&dst[(size_t)bh * 16384 + t * 64 + d0]) = o.u;
        }
      }
    } else {
      // V^T store: lane holds n_g (fixed) -> d, m = mbase+i*16+quad*4+r.
      // pos(t0+r) = pos(t0)+r (t0 4-aligned) -> 4 consecutive tt.
#pragma unroll
      for (int j = 0; j < 4; ++j) {
        int n_g = nbase + j * 16 + l15;
        int c = n_g - 768;
        int d = c & 63;
        int h = c >> 6;
#pragma unroll
        for (int i = 0; i < 4; ++i) {
          int m_loc = mbase + i * 16 + quad * 4;
          int b = m_loc >> 8, t0 = m_loc & 255;
          int rr = t0 & 31;
          int pos0 = (((rr & 15) >> 2) << 3) | ((rr >> 4) << 2);
          int tt0 = (t0 & ~31) | pos0;
          int bh = b * 6 + h;
          union { bf16 h4[4]; uint2 u; } o;
#pragma unroll
          for (int r = 0; r < 4; ++r) o.h4[r] = __float2bfloat16(acc[i][j][r]);
          *(uint2*)(&vb[(size_t)bh * 16384 + d * 256 + tt0]) = o.u;
        }
      }
    }
  } else {
    // proj (SWAP): lane holds m (fixed), 4 consecutive n -> float4/uint2 store.
    const int f32io = *flag;
#pragma unroll
    for (int j = 0; j < 4; ++j) {
      int ng0 = nbase + j * 16 + quad * 4;
      float b0, b1, b2, b3;
      if (f32io) {
        float4 bb = *(const float4*)((const float*)bias + ng0);
        b0 = bb.x; b1 = bb.y; b2 = bb.z; b3 = bb.w;
      } else {
        const bf16* bp = (const bf16*)bias + ng0;
        b0 = __bfloat162float(bp[0]); b1 = __bfloat162float(bp[1]);
        b2 = __bfloat162float(bp[2]); b3 = __bfloat162float(bp[3]);
      }
#pragma unroll
      for (int i = 0; i < 4; ++i) {
        int m_loc = mbase + i * 16 + l15;
        size_t o = (size_t)(r_off + m_loc) * 384 + ng0;
        if (f32io) {
          float4 v;
          v.x = acc[i][j][0] + b0; v.y = acc[i][j][1] + b1;
          v.z = acc[i][j][2] + b2; v.w = acc[i][j][3] + b3;
          *(float4*)((float*)outp + o) = v;
        } else {
          union { bf16 h4[4]; uint2 u; } ov;
          ov.h4[0] = __float2bfloat16(acc[i][j][0] + b0);
          ov.h4[1] = __float2bfloat16(acc[i][j][1] + b1);
          ov.h4[2] = __float2bfloat16(acc[i][j][2] + b2);
          ov.h4[3] = __float2bfloat16(acc[i][j][3] + b3);
          *(uint2*)((bf16*)outp + o) = ov.u;
        }
      }
    }
  }
}

// ---------------- causal attention: zero-LDS, paired chains, deep prefetch --
// grid: nb*12 blocks (bh, pair p); wave w owns TWO 16-row q-tiles of head bh:
//   jA = p*4+w (tiles 0..7) and jB = 15-jA (tiles 8..15).
// Total 32-key chunks per wave = ktA+ktB = 9 for every wave (balanced), and
// the two chains share K/V loads + interleave for ILP. Register-P trick:
// packed S output IS the PV B-fragment under key-permutation pi; V^T is
// stored pre-permuted by the gemm so vf is one s16x8 per dt.
// Pipeline: K ring 3 bufs (2 chunks ahead), V 2 bufs (1 ahead). No LDS.
__global__ __launch_bounds__(256, 3) void attn_kernel(const bf16* __restrict__ Q,
                                                      const bf16* __restrict__ Kb,
                                                      const bf16* __restrict__ Vt,
                                                      bf16* __restrict__ attn_out) {
  const int tid = threadIdx.x;
  const int lane = tid & 63;
  const int wave = tid >> 6;
  const int l15 = lane & 15, quad = lane >> 4;
  const int nblk = gridDim.x;
  int blk = blockIdx.x;
  if ((nblk & 7) == 0)  // bijective XCD swizzle (both blocks of a head -> same XCD L2)
    blk = (blockIdx.x & 7) * (nblk >> 3) + (blockIdx.x >> 3);
  const int p = blk & 1;
  const int bh = blk >> 1;
  const int jA = p * 4 + wave;   // light chain: tiles 0..7
  const int jB = 15 - jA;        // heavy chain: tiles 8..15
  const size_t base = (size_t)bh * 16384;
  const int q0A = jA * 16, q0B = jB * 16;

  // Q fragments (B-operand: n = l15 = q-row, k = quad*8+j = d)
  s16x8 qA0 = *(const s16x8*)(&Q[base + (q0A + l15) * 64 + quad * 8]);
  s16x8 qA1 = *(const s16x8*)(&Q[base + (q0A + l15) * 64 + 32 + quad * 8]);
  s16x8 qB0 = *(const s16x8*)(&Q[base + (q0B + l15) * 64 + quad * 8]);
  s16x8 qB1 = *(const s16x8*)(&Q[base + (q0B + l15) * 64 + 32 + quad * 8]);

  const int ktA = (jA + 2) >> 1;   // 1..4 chunks
  const int ktB = (jB + 2) >> 1;   // 4..8 chunks (>= ktA)
  const int tqA = q0A + l15, tqB = q0B + l15;
  const f32x4 z4 = {0.f, 0.f, 0.f, 0.f};

  const bf16* Kp = Kb + base + (size_t)l15 * 64 + quad * 8;
  const bf16* Vp = Vt + base + (size_t)l15 * 256 + quad * 8;

  typedef union { s16x8 v; uint32_t w[4]; } pf_t;

  // K ring (3 bufs, 2 ahead): [buf][hf*2 + d-half]; V ring (2 bufs, 1 ahead)
  s16x8 kf[3][4];
  s16x8 vf[2][4];
#pragma unroll
  for (int i = 0; i < 4; ++i) {
    kf[0][i] = *(const s16x8*)(Kp + (size_t)((i >> 1) * 16) * 64 + (i & 1) * 32);
    kf[1][i] = *(const s16x8*)(Kp + (size_t)(32 + (i >> 1) * 16) * 64 + (i & 1) * 32);
  }
#pragma unroll
  for (int dt = 0; dt < 4; ++dt) vf[0][dt] = *(const s16x8*)(Vp + (size_t)dt * 4096);

  f32x4 ofA[4], ofB[4];
#pragma unroll
  for (int dt = 0; dt < 4; ++dt) { ofA[dt] = z4; ofB[dt] = z4; }
  float rsA = 0.f, rsB = 0.f;

#pragma unroll
  for (int t = 0; t < 8; ++t) {
    if (t < ktB) {  // wave-uniform
      // prefetch K[t+2], V[t+1]
      if (t + 2 < ktB) {
        const bf16* Kn = Kp + (size_t)(t + 2) * 32 * 64;
#pragma unroll
        for (int i = 0; i < 4; ++i)
          kf[(t + 2) % 3][i] = *(const s16x8*)(Kn + (size_t)((i >> 1) * 16) * 64 + (i & 1) * 32);
      }
      if (t + 1 < ktB) {
#pragma unroll
        for (int dt = 0; dt < 4; ++dt)
          vf[(t + 1) & 1][dt] = *(const s16x8*)(Vp + (size_t)dt * 4096 + (t + 1) * 32);
      }
      // ---- chain B (always active while t < ktB) ----
      pf_t pfB;
#pragma unroll
      for (int hf = 0; hf < 2; ++hf) {
        const int nt = 2 * t + hf;
        if (nt <= jB) {  // wave-uniform
          f32x4 s = MFMA16(kf[t % 3][hf * 2 + 0], qB0, z4);
          s = MFMA16(kf[t % 3][hf * 2 + 1], qB1, s);
          const int tk0 = nt * 16 + quad * 4;
          float p0 = (tk0 + 0 <= tqB) ? __expf(s[0] * 0.125f) : 0.f;
          float p1 = (tk0 + 1 <= tqB) ? __expf(s[1] * 0.125f) : 0.f;
          float p2 = (tk0 + 2 <= tqB) ? __expf(s[2] * 0.125f) : 0.f;
          float p3 = (tk0 + 3 <= tqB) ? __expf(s[3] * 0.125f) : 0.f;
          rsB += (p0 + p1) + (p2 + p3);
          union { bf16 hh[2]; uint32_t u; } w0, w1;
          w0.hh[0] = __float2bfloat16(p0); w0.hh[1] = __float2bfloat16(p1);
          w1.hh[0] = __float2bfloat16(p2); w1.hh[1] = __float2bfloat16(p3);
          pfB.w[hf * 2 + 0] = w0.u;
          pfB.w[hf * 2 + 1] = w1.u;
        } else {
          pfB.w[hf * 2 + 0] = 0u;
          pfB.w[hf * 2 + 1] = 0u;
        }
      }
      // ---- chain A (first ktA chunks) ----
      if (t < ktA) {  // wave-uniform
        pf_t pfA;
#pragma unroll
        for (int hf = 0; hf < 2; ++hf) {
          const int nt = 2 * t + hf;
          if (nt <= jA) {  // wave-uniform
            f32x4 s = MFMA16(kf[t % 3][hf * 2 + 0], qA0, z4);
            s = MFMA16(kf[t % 3][hf * 2 + 1], qA1, s);
            const int tk0 = nt * 16 + quad * 4;
            float p0 = (tk0 + 0 <= tqA) ? __expf(s[0] * 0.125f) : 0.f;
            float p1 = (tk0 + 1 <= tqA) ? __expf(s[1] * 0.125f) : 0.f;
            float p2 = (tk0 + 2 <= tqA) ? __expf(s[2] * 0.125f) : 0.f;
            float p3 = (tk0 + 3 <= tqA) ? __expf(s[3] * 0.125f) : 0.f;
            rsA += (p0 + p1) + (p2 + p3);
            union { bf16 hh[2]; uint32_t u; } w0, w1;
            w0.hh[0] = __float2bfloat16(p0); w0.hh[1] = __float2bfloat16(p1);
            w1.hh[0] = __float2bfloat16(p2); w1.hh[1] = __float2bfloat16(p3);
            pfA.w[hf * 2 + 0] = w0.u;
            pfA.w[hf * 2 + 1] = w1.u;
          } else {
            pfA.w[hf * 2 + 0] = 0u;
            pfA.w[hf * 2 + 1] = 0u;
          }
        }
#pragma unroll
        for (int dt = 0; dt < 4; ++dt) ofA[dt] = MFMA16(vf[t & 1][dt], pfA.v, ofA[dt]);
      }
#pragma unroll
      for (int dt = 0; dt < 4; ++dt) ofB[dt] = MFMA16(vf[t & 1][dt], pfB.v, ofB[dt]);
    }
  }

  rsA += __shfl_xor(rsA, 16);
  rsA += __shfl_xor(rsA, 32);
  rsB += __shfl_xor(rsB, 16);
  rsB += __shfl_xor(rsB, 32);
  const float invA = 1.0f / rsA;
  const float invB = 1.0f / rsB;

  const int b = bh / 6;
  const int h = bh - b * 6;
  const size_t orowA = (size_t)(b * 256 + q0A + l15) * 384 + h * 64;
  const size_t orowB = (size_t)(b * 256 + q0B + l15) * 384 + h * 64;
#pragma unroll
  for (int dt = 0; dt < 4; ++dt) {
    union { bf16 h4[4]; uint2 u; } oa, ob;
#pragma unroll
    for (int r = 0; r < 4; ++r) {
      oa.h4[r] = __float2bfloat16(ofA[dt][r] * invA);
      ob.h4[r] = __float2bfloat16(ofB[dt][r] * invB);
    }
    *(uint2*)(&attn_out[orowA + dt * 16 + quad * 4]) = oa.u;
    *(uint2*)(&attn_out[orowB + dt * 16 + quad * 4]) = ob.u;
  }
}

// ---------------- launcher ----------------
extern "C" void kernel_launch(void* const* d_in, const int* in_sizes, int n_in,
                              void* d_out, int out_size, void* d_ws, size_t ws_size,
                              hipStream_t stream) {
  const void* x = d_in[0];       // [256,256,384]  fp32 or bf16 (detected)
  const void* Wqkv = d_in[1];    // [384,1152]
  const void* Wproj = d_in[2];   // [384,384]
  const void* bproj = d_in[3];   // [384]

  char* ws = (char*)d_ws;
  int* flag = (int*)ws;                ws += 256;
  bf16* Wt_qkv = (bf16*)ws;            ws += (size_t)1152 * 384 * 2;
  bf16* Wt_proj = (bf16*)ws;           ws += (size_t)384 * 384 * 2;

  const size_t per_batch = (size_t)5 * 98304 * 2;  // xb,q,k,vt,attn per batch
  size_t used = (size_t)(ws - (char*)d_ws);
  size_t remain = (ws_size > used) ? (ws_size - used) : 0;
  int NB = (int)(remain / per_batch);
  if (NB > 256) NB = 256;
  if (NB < 1) NB = 1;

  bf16* xb_buf = (bf16*)ws;
  bf16* q_buf = xb_buf + (size_t)NB * 98304;
  bf16* k_buf = q_buf + (size_t)NB * 98304;
  bf16* vt_buf = k_buf + (size_t)NB * 98304;
  bf16* attn_buf = vt_buf + (size_t)NB * 98304;

  detect_kernel<<<1, 256, 0, stream>>>(x, flag);
  transpose_kernel<<<(384 * 1152 + 255) / 256, 256, 0, stream>>>(Wqkv, Wt_qkv, 384, 1152, flag);
  transpose_kernel<<<(384 * 384 + 255) / 256, 256, 0, stream>>>(Wproj, Wt_proj, 384, 384, flag);

  for (int b0 = 0; b0 < 256; b0 += NB) {
    int nb = (256 - b0 < NB) ? (256 - b0) : NB;
    int r_off = b0 * 256;
    convert_kernel<<<nb * 48, 256, 0, stream>>>(x, xb_buf, (size_t)r_off * 384, flag);
    // Q,K in C^T orientation (vectorized d-stores)
    gemm_kernel<0, true><<<dim3(6, 2 * nb), 256, 0, stream>>>(
        xb_buf, Wt_qkv, q_buf, k_buf, vt_buf, nullptr, nullptr, 0, 0, flag);
    // V in original orientation (vectorized tt-stores via 4-aligned pi)
    gemm_kernel<0, false><<<dim3(3, 2 * nb), 256, 0, stream>>>(
        xb_buf, Wt_qkv, q_buf, k_buf, vt_buf, nullptr, nullptr, 0, 6, flag);
    attn_kernel<<<nb * 12, 256, 0, stream>>>(q_buf, k_buf, vt_buf, attn_buf);
    gemm_kernel<1, true><<<dim3(3, 2 * nb), 256, 0, stream>>>(
        attn_buf, Wt_proj, nullptr, nullptr, nullptr, d_out, bproj, r_off, 0, flag);
  }
}